// Round 6
// baseline (332.896 us; speedup 1.0000x reference)
//
#include <hip/hip_runtime.h>
#include <hip/hip_bf16.h>
#include <hip/hip_fp16.h>

// Problem constants (match reference)
constexpr int IMG_ = 256;
constexpr int M_   = 1920;   // N_SHOTS * N_SAMPLES
constexpr int B_   = 64;
constexpr int MI_  = M_ * IMG_;          // 491520 elements per phase table
constexpr int IMG2 = IMG_ * IMG_;        // 65536

typedef _Float16 half8 __attribute__((ext_vector_type(8)));
typedef float    floatx4 __attribute__((ext_vector_type(4)));

// global -> LDS direct copy, 16B per lane; LDS dest is wave-uniform base + lane*16
__device__ __forceinline__ void gll16(const _Float16* g, _Float16* l) {
  __builtin_amdgcn_global_load_lds(
      (const __attribute__((address_space(1))) void*)g,
      (__attribute__((address_space(3))) void*)l, 16, 0, 0);
}

// ---------------------------------------------------------------------------
// prep_k: fused {phase1 | phase2 | x-transpose} by blockIdx range (independent
// work; whole blocks take one branch).
// ---------------------------------------------------------------------------
constexpr int PH1_N = MI_ / 256;          // 1920
constexpr int PH2_N = 8 * IMG_;           // 2048
constexpr int XT_N  = 8 * 8 * B_;         // 4096

__global__ __launch_bounds__(256) void prep_k(
    const float* __restrict__ samples,
    const float* __restrict__ xr, const float* __restrict__ xi,
    _Float16* __restrict__ axh_r, _Float16* __restrict__ axh_i,
    _Float16* __restrict__ ayh_r, _Float16* __restrict__ ayh_i,
    _Float16* __restrict__ axtc_r, _Float16* __restrict__ axtc_i,
    _Float16* __restrict__ aytc_r, _Float16* __restrict__ aytc_i,
    _Float16* __restrict__ xth_r, _Float16* __restrict__ xth_i) {
  __shared__ float tr[32][33], ti[32][33];
  const int t = threadIdx.x;
  const int n = blockIdx.x;

  if (n < PH1_N) {
    // phase tables, natural layout [m][i]
    int idx = n * 256 + t;
    int m = idx >> 8;
    int i = idx & 255;
    float g  = (float)i - 128.0f;
    float kx = samples[2 * m + 0];
    float ky = samples[2 * m + 1];
    float sx, cx, sy, cy;
    sincospif(-2.0f * kx * g, &sx, &cx);
    sincospif(-2.0f * ky * g, &sy, &cy);
    axh_r[idx] = (_Float16)cx; axh_i[idx] = (_Float16)sx;
    ayh_r[idx] = (_Float16)cy; ayh_i[idx] = (_Float16)sy;
  } else if (n < PH1_N + PH2_N) {
    // transposed, pre-conjugated tables [i][m]
    int nn = n - PH1_N;
    int m = (nn & 7) * 256 + t;
    int i = nn >> 3;
    if (m < M_) {               // guard: m decode spans 2048 > M_
      float g  = (float)i - 128.0f;
      float kx = samples[2 * m + 0];
      float ky = samples[2 * m + 1];
      float sx, cx, sy, cy;
      sincospif(-2.0f * kx * g, &sx, &cx);
      sincospif(-2.0f * ky * g, &sy, &cy);
      int o = i * M_ + m;
      axtc_r[o] = (_Float16)cx; axtc_i[o] = (_Float16)(-sx);
      aytc_r[o] = (_Float16)cy; aytc_i[o] = (_Float16)(-sy);
    }
  } else {
    // X transpose + f16 convert: xth[b][j][i] = x[b][i][j]
    int nn = n - PH1_N - PH2_N;
    const int b  = nn >> 6;
    const int i0 = (nn & 7) * 32, j0 = ((nn >> 3) & 7) * 32;
    const int r = t >> 5, c = t & 31;
#pragma unroll
    for (int k = 0; k < 4; ++k) {
      int row = r + k * 8;
      tr[row][c] = xr[(size_t)b * IMG2 + (i0 + row) * IMG_ + j0 + c];
      ti[row][c] = xi[(size_t)b * IMG2 + (i0 + row) * IMG_ + j0 + c];
    }
    __syncthreads();
#pragma unroll
    for (int k = 0; k < 4; ++k) {
      int row = r + k * 8;
      xth_r[(size_t)b * IMG2 + (j0 + row) * IMG_ + i0 + c] = (_Float16)tr[c][row];
      xth_i[(size_t)b * IMG2 + (j0 + row) * IMG_ + i0 + c] = (_Float16)ti[c][row];
    }
  }
}

// ---------------------------------------------------------------------------
// LDS swizzle (both GEMMs), per 32-half (64B) row of 4 16B chunks:
// physical chunk p of row r holds logical chunk p ^ ((r>>1)&3).
//  - staging via global_load_lds: HW writes lane-linear (lane l -> row l>>2,
//    phys chunk l&3); lane fetches global logical chunk (l&3)^((l>>3)&3).
//  - ds_read_b128 frags read phys chunk q ^ ((lr>>1)&3): zero bank conflicts
//    (measured rounds 1-5: SQ_LDS_BANK_CONFLICT = 0).
// ---------------------------------------------------------------------------

// ---------------------------------------------------------------------------
// Forward NDFT via f16 MFMA + fused Ay-weighted j-reduction + density.
//   kw[b,m] = density[m] * sum_j Ay[m,j] * (sum_i Ax[m,i] * X_b[i,j])
// Block: 256 thr = 4 waves; block tile 64m x 128j per jc, jc in {0,1} -> 16
// k-steps per block.
// ROUND-6 SPILL FIX (52 MB scratch in r3/r5): (a) __launch_bounds__(256)
// without a min-waves clamp -- (256,3) capped unified VGPR+AGPR at ~170/wave
// and forced ~27 KB/block scratch (VGPR_Count pinned at 84); (b) s-loop
// unroll 2 (buf-parity only) instead of full unroll -- full unroll hoisted
// 16 steps of staging address math into live registers. adj_k (unroll 2,
// no spill signature) is the existence proof for this combination.
// Grid 1920 1-D, XCD-grouped: xcd = n&7, 30 consecutive blocks share b.
// ---------------------------------------------------------------------------
__global__ __launch_bounds__(256) void fwd_k(
    const _Float16* __restrict__ axh_r, const _Float16* __restrict__ axh_i,
    const _Float16* __restrict__ ayh_r, const _Float16* __restrict__ ayh_i,
    const _Float16* __restrict__ xth_r, const _Float16* __restrict__ xth_i,
    const float* __restrict__ density,
    _Float16* __restrict__ kwh_r, _Float16* __restrict__ kwh_i) {
  __shared__ _Float16 lds[2][12288];   // 48 KB staging
  __shared__ float2 scr[4][64];        // 2 KB per-wave m-partials (separate!)

  const int t  = threadIdx.x;
  const int w  = t >> 6;
  const int l  = t & 63;
  const int lr = l & 15;   // frag row within 16-tile; C col (j)
  const int q  = l >> 4;   // k-chunk; C row group (m)

  const int n   = blockIdx.x;        // 0..1919
  const int xcd = n & 7;
  const int r   = n >> 3;            // 0..239
  const int b   = xcd + 8 * (r / 30);
  const int m0  = (r % 30) * 64;

  const int srow   = l >> 2;                      // staging row within 16
  const int schunk = (l & 3) ^ ((l >> 3) & 3);    // pre-swizzled global chunk
  const int gA     = srow * IMG_ + schunk * 8;    // halfs
  const int rc     = (q ^ ((lr >> 1) & 3)) << 3;  // frag-read swizzled chunk

  const floatx4 z4 = {0.f, 0.f, 0.f, 0.f};
  floatx4 accr[4][2], acci[4][2];
#pragma unroll
  for (int mt = 0; mt < 4; ++mt)
#pragma unroll
    for (int jt = 0; jt < 2; ++jt) { accr[mt][jt] = z4; acci[mt][jt] = z4; }

  auto stage = [&](int buf, int s) {
    const int jc  = s >> 3;
    const int col = (s & 7) * 32;
    _Float16* L = lds[buf];
    const size_t offA = (size_t)(m0 + w * 16) * IMG_ + col + gA;
    gll16(axh_r + offA, L + 0    + w * 512);
    gll16(axh_i + offA, L + 2048 + w * 512);
    const size_t offB = (size_t)b * IMG2 + (size_t)(jc * 128 + w * 32) * IMG_ + col + gA;
    gll16(xth_r + offB,             L + 4096 + w * 1024);
    gll16(xth_r + offB + 16 * IMG_, L + 4096 + w * 1024 + 512);
    gll16(xth_i + offB,             L + 8192 + w * 1024);
    gll16(xth_i + offB + 16 * IMG_, L + 8192 + w * 1024 + 512);
  };

  auto compute = [&](int buf) {
    const _Float16* L = lds[buf];
    half8 br[2], bi[2], nbi[2];
#pragma unroll
    for (int jt = 0; jt < 2; ++jt) {
      const int ro = (w * 32 + jt * 16 + lr) * 32 + rc;
      br[jt]  = *(const half8*)&L[4096 + ro];
      bi[jt]  = *(const half8*)&L[8192 + ro];
      nbi[jt] = -bi[jt];
    }
#pragma unroll
    for (int mt = 0; mt < 4; ++mt) {
      const int ro = (mt * 16 + lr) * 32 + rc;
      half8 ar = *(const half8*)&L[0 + ro];
      half8 ai = *(const half8*)&L[2048 + ro];
#pragma unroll
      for (int jt = 0; jt < 2; ++jt) {
        accr[mt][jt] = __builtin_amdgcn_mfma_f32_16x16x32_f16(ar, br[jt],  accr[mt][jt], 0, 0, 0);
        accr[mt][jt] = __builtin_amdgcn_mfma_f32_16x16x32_f16(ai, nbi[jt], accr[mt][jt], 0, 0, 0);
        acci[mt][jt] = __builtin_amdgcn_mfma_f32_16x16x32_f16(ar, bi[jt],  acci[mt][jt], 0, 0, 0);
        acci[mt][jt] = __builtin_amdgcn_mfma_f32_16x16x32_f16(ai, br[jt],  acci[mt][jt], 0, 0, 0);
      }
    }
  };

  // Streaming epilogue: per mt, fold Ay-weighted j-sum, shfl-reduce over the
  // 16 j-lanes, park in scr (per-wave slice). Only 8 f32 live at a time.
  auto epi = [&](int jc) {
#pragma unroll
    for (int mt = 0; mt < 4; ++mt) {
      float kr[4] = {}, ki[4] = {};
#pragma unroll
      for (int jt = 0; jt < 2; ++jt) {
        const int j = jc * 128 + w * 32 + jt * 16 + lr;
#pragma unroll
        for (int reg = 0; reg < 4; ++reg) {
          const int m = m0 + mt * 16 + q * 4 + reg;
          const float yr = (float)ayh_r[m * IMG_ + j];
          const float yi = (float)ayh_i[m * IMG_ + j];
          const float tr = accr[mt][jt][reg], ti = acci[mt][jt][reg];
          kr[reg] = fmaf(yr, tr, fmaf(-yi, ti, kr[reg]));
          ki[reg] = fmaf(yr, ti, fmaf(yi, tr, ki[reg]));
        }
        accr[mt][jt] = z4;
        acci[mt][jt] = z4;
      }
#pragma unroll
      for (int reg = 0; reg < 4; ++reg)
#pragma unroll
        for (int off = 1; off < 16; off <<= 1) {
          kr[reg] += __shfl_xor(kr[reg], off);
          ki[reg] += __shfl_xor(ki[reg], off);
        }
      if (lr == 0) {
#pragma unroll
        for (int reg = 0; reg < 4; ++reg) {
          const int ml = mt * 16 + q * 4 + reg;
          if (jc == 0) {
            scr[w][ml] = make_float2(kr[reg], ki[reg]);
          } else {
            float2 p = scr[w][ml];
            scr[w][ml] = make_float2(p.x + kr[reg], p.y + ki[reg]);
          }
        }
      }
    }
  };

  stage(0, 0);
  __syncthreads();               // implicit vmcnt(0) drains global_load_lds
#pragma unroll 2
  for (int s = 0; s < 16; ++s) {
    const int buf = s & 1;
    if (s < 15) stage(buf ^ 1, s + 1);    // next-tile loads overlap MFMA
    compute(buf);
    if (s == 7) epi(0);                   // overlaps in-flight stage(8) loads
    __syncthreads();
  }
  epi(1);
  __syncthreads();

  // cross-wave combine (4 j-slices), density, final f16 kw write
  if (t < 64) {
    float sr = 0.f, si = 0.f;
#pragma unroll
    for (int ww = 0; ww < 4; ++ww) {
      const float2 p = scr[ww][t];
      sr += p.x; si += p.y;
    }
    const int m = m0 + t;
    const float d = density[m];
    kwh_r[b * M_ + m] = (_Float16)(sr * d);
    kwh_i[b * M_ + m] = (_Float16)(si * d);
  }
}

// ---------------------------------------------------------------------------
// Adjoint NDFT via f16 MFMA:
//   out[b,i,j] = (1/IMG^2) sum_m conj(Ax)[m,i] * kw[b,m] * conj(Ay)[m,j]
// Block tile 64i x 64j, 4 waves of 32x32 (acc 64), LDS 32 KB -> 3 blocks/CU
// = 12 waves/CU. K = 1920, 60 double-buffered steps. (unchanged this round)
// Grid 1024 1-D, XCD-grouped: xcd = n&7 owns 2 (i0,j0) combos x 64 b.
// ---------------------------------------------------------------------------
__global__ __launch_bounds__(256, 3) void adj_k(
    const _Float16* __restrict__ axtc_r, const _Float16* __restrict__ axtc_i,
    const _Float16* __restrict__ aytc_r, const _Float16* __restrict__ aytc_i,
    const _Float16* __restrict__ kwh_r, const _Float16* __restrict__ kwh_i,
    float* __restrict__ out) {
  __shared__ _Float16 lds[2][8192];    // 32 KB: {A_r,A_i,W_r,W_i} x dbuf

  const int t  = threadIdx.x;
  const int w  = t >> 6;
  const int l  = t & 63;
  const int lr = l & 15;
  const int q  = l >> 4;
  const int wi = w >> 1;               // 2 wave-rows (i)
  const int wj = w & 1;                // 2 wave-cols (j)

  const int n     = blockIdx.x;        // 0..1023
  const int xcd   = n & 7;
  const int r     = n >> 3;            // 0..127
  const int combo = xcd + 8 * (r >> 6);  // 0..15
  const int b     = r & 63;
  const int i0    = (combo >> 2) * 64;
  const int j0    = (combo & 3) * 64;

  const int srow   = l >> 2;
  const int schunk = (l & 3) ^ ((l >> 3) & 3);
  const int gA     = srow * M_ + schunk * 8;      // A row stride = 1920 halfs
  const int rc     = (q ^ ((lr >> 1) & 3)) << 3;

  // W staging: thread -> (j-row = t>>2, 8-half seg = t&3); swizzled b128 write
  const int wrow = t >> 2;
  const int wseg = t & 3;
  const int wsc  = wseg ^ ((wrow >> 1) & 3);      // logical (global) chunk

  const floatx4 z4 = {0.f, 0.f, 0.f, 0.f};
  floatx4 accr[2][2], acci[2][2];
#pragma unroll
  for (int mt = 0; mt < 2; ++mt)
#pragma unroll
    for (int jt = 0; jt < 2; ++jt) { accr[mt][jt] = z4; acci[mt][jt] = z4; }

  uint4 Yr, Yi, Cr, Ci;

  auto stageA = [&](int buf, int s) {
    const int mc = s * 32;
    _Float16* L = lds[buf];
    const size_t off = (size_t)(i0 + w * 16) * M_ + mc + gA;
    gll16(axtc_r + off, L + 0    + w * 512);
    gll16(axtc_i + off, L + 2048 + w * 512);
  };

  auto loadW = [&](int s) {   // issue early; consumed by writeW after compute
    const int mc = s * 32 + wsc * 8;
    const size_t oy = (size_t)(j0 + wrow) * M_ + mc;
    const size_t oc = (size_t)b * M_ + mc;
    Yr = *(const uint4*)&aytc_r[oy];
    Yi = *(const uint4*)&aytc_i[oy];
    Cr = *(const uint4*)&kwh_r[oc];
    Ci = *(const uint4*)&kwh_i[oc];
  };

  auto writeW = [&](int buf) {
    __half2 Wr[4], Wi2[4];
    const __half2* yr = (const __half2*)&Yr; const __half2* yi = (const __half2*)&Yi;
    const __half2* cr = (const __half2*)&Cr; const __half2* ci = (const __half2*)&Ci;
#pragma unroll
    for (int e = 0; e < 4; ++e) {
      Wr[e]  = __hsub2(__hmul2(cr[e], yr[e]), __hmul2(ci[e], yi[e]));
      Wi2[e] = __hfma2(cr[e], yi[e], __hmul2(ci[e], yr[e]));
    }
    _Float16* Lr = lds[buf] + 4096;
    _Float16* Li = lds[buf] + 6144;
    const int o = wrow * 32 + wseg * 8;
    *(uint4*)&Lr[o] = *(const uint4*)&Wr[0];
    *(uint4*)&Li[o] = *(const uint4*)&Wi2[0];
  };

  auto compute = [&](int buf) {
    const _Float16* L = lds[buf];
    half8 br[2], bi[2], nbi[2];
#pragma unroll
    for (int jt = 0; jt < 2; ++jt) {
      const int ro = (wj * 32 + jt * 16 + lr) * 32 + rc;
      br[jt]  = *(const half8*)&L[4096 + ro];
      bi[jt]  = *(const half8*)&L[6144 + ro];
      nbi[jt] = -bi[jt];
    }
#pragma unroll
    for (int mt = 0; mt < 2; ++mt) {
      const int ro = (wi * 32 + mt * 16 + lr) * 32 + rc;
      half8 ar = *(const half8*)&L[0 + ro];
      half8 ai = *(const half8*)&L[2048 + ro];
#pragma unroll
      for (int jt = 0; jt < 2; ++jt) {
        accr[mt][jt] = __builtin_amdgcn_mfma_f32_16x16x32_f16(ar, br[jt],  accr[mt][jt], 0, 0, 0);
        accr[mt][jt] = __builtin_amdgcn_mfma_f32_16x16x32_f16(ai, nbi[jt], accr[mt][jt], 0, 0, 0);
        acci[mt][jt] = __builtin_amdgcn_mfma_f32_16x16x32_f16(ar, bi[jt],  acci[mt][jt], 0, 0, 0);
        acci[mt][jt] = __builtin_amdgcn_mfma_f32_16x16x32_f16(ai, br[jt],  acci[mt][jt], 0, 0, 0);
      }
    }
  };

  loadW(0);
  stageA(0, 0);
  writeW(0);
  __syncthreads();
#pragma unroll 2
  for (int s = 0; s < 60; ++s) {
    const int buf = s & 1;
    if (s < 59) { stageA(buf ^ 1, s + 1); loadW(s + 1); }
    compute(buf);
    if (s < 59) writeW(buf ^ 1);
    __syncthreads();
  }

  const float sc = 1.0f / (float)IMG2;
#pragma unroll
  for (int mt = 0; mt < 2; ++mt)
#pragma unroll
    for (int jt = 0; jt < 2; ++jt) {
      const int jg = j0 + wj * 32 + jt * 16 + lr;
#pragma unroll
      for (int reg = 0; reg < 4; ++reg) {
        const int ig = i0 + wi * 32 + mt * 16 + q * 4 + reg;
        float2 v = make_float2(accr[mt][jt][reg] * sc, acci[mt][jt][reg] * sc);
        *(float2*)&out[((size_t)(b * IMG_ + ig) * IMG_ + jg) * 2] = v;
      }
    }
}

// ---------------------------------------------------------------------------
// Launch: 3 kernels.
// ---------------------------------------------------------------------------
extern "C" void kernel_launch(void* const* d_in, const int* in_sizes, int n_in,
                              void* d_out, int out_size, void* d_ws, size_t ws_size,
                              hipStream_t stream) {
  (void)in_sizes; (void)n_in; (void)out_size; (void)ws_size;

  const float* xr      = (const float*)d_in[0];
  const float* xi      = (const float*)d_in[1];
  const float* samples = (const float*)d_in[2];
  const float* density = (const float*)d_in[3];
  float* out = (float*)d_out;

  // ws: 10 f16 arrays, 8.36 MB total
  _Float16* f = (_Float16*)d_ws;
  _Float16* axh_r  = f + 0 * MI_;
  _Float16* axh_i  = f + 1 * MI_;
  _Float16* ayh_r  = f + 2 * MI_;
  _Float16* ayh_i  = f + 3 * MI_;
  _Float16* axtc_r = f + 4 * MI_;
  _Float16* axtc_i = f + 5 * MI_;
  _Float16* aytc_r = f + 6 * MI_;
  _Float16* aytc_i = f + 7 * MI_;
  _Float16* kwh_r  = f + 8 * MI_;
  _Float16* kwh_i  = kwh_r + B_ * M_;

  // X^T (f16) parked in d_out; fully consumed by fwd_k before adj_k overwrites.
  _Float16* xth_r = (_Float16*)d_out;
  _Float16* xth_i = xth_r + (size_t)B_ * IMG2;

  prep_k<<<PH1_N + PH2_N + XT_N, 256, 0, stream>>>(
      samples, xr, xi, axh_r, axh_i, ayh_r, ayh_i,
      axtc_r, axtc_i, aytc_r, aytc_i, xth_r, xth_i);
  fwd_k<<<1920, 256, 0, stream>>>(axh_r, axh_i, ayh_r, ayh_i,
                                  xth_r, xth_i, density, kwh_r, kwh_i);
  adj_k<<<1024, 256, 0, stream>>>(axtc_r, axtc_i, aytc_r, aytc_i,
                                  kwh_r, kwh_i, out);
}

// Round 7
// 322.122 us; speedup vs baseline: 1.0334x; 1.0334x over previous
//
#include <hip/hip_runtime.h>
#include <hip/hip_bf16.h>
#include <hip/hip_fp16.h>

// Problem constants (match reference)
constexpr int IMG_ = 256;
constexpr int M_   = 1920;   // N_SHOTS * N_SAMPLES
constexpr int B_   = 64;
constexpr int MI_  = M_ * IMG_;          // 491520 elements per phase table
constexpr int IMG2 = IMG_ * IMG_;        // 65536

typedef _Float16 half8 __attribute__((ext_vector_type(8)));
typedef float    floatx4 __attribute__((ext_vector_type(4)));

// global -> LDS direct copy, 16B per lane; LDS dest is wave-uniform base + lane*16
__device__ __forceinline__ void gll16(const _Float16* g, _Float16* l) {
  __builtin_amdgcn_global_load_lds(
      (const __attribute__((address_space(1))) void*)g,
      (__attribute__((address_space(3))) void*)l, 16, 0, 0);
}

// ---------------------------------------------------------------------------
// prep_k: fused {phase1 | phase2 | x-transpose} by blockIdx range (r5-proven).
// ---------------------------------------------------------------------------
constexpr int PH1_N = MI_ / 256;          // 1920
constexpr int PH2_N = 8 * IMG_;           // 2048
constexpr int XT_N  = 8 * 8 * B_;         // 4096

__global__ __launch_bounds__(256) void prep_k(
    const float* __restrict__ samples,
    const float* __restrict__ xr, const float* __restrict__ xi,
    _Float16* __restrict__ axh_r, _Float16* __restrict__ axh_i,
    _Float16* __restrict__ ayh_r, _Float16* __restrict__ ayh_i,
    _Float16* __restrict__ axtc_r, _Float16* __restrict__ axtc_i,
    _Float16* __restrict__ aytc_r, _Float16* __restrict__ aytc_i,
    _Float16* __restrict__ xth_r, _Float16* __restrict__ xth_i) {
  __shared__ float tr[32][33], ti[32][33];
  const int t = threadIdx.x;
  const int n = blockIdx.x;

  if (n < PH1_N) {
    int idx = n * 256 + t;
    int m = idx >> 8;
    int i = idx & 255;
    float g  = (float)i - 128.0f;
    float kx = samples[2 * m + 0];
    float ky = samples[2 * m + 1];
    float sx, cx, sy, cy;
    sincospif(-2.0f * kx * g, &sx, &cx);
    sincospif(-2.0f * ky * g, &sy, &cy);
    axh_r[idx] = (_Float16)cx; axh_i[idx] = (_Float16)sx;
    ayh_r[idx] = (_Float16)cy; ayh_i[idx] = (_Float16)sy;
  } else if (n < PH1_N + PH2_N) {
    int nn = n - PH1_N;
    int m = (nn & 7) * 256 + t;
    int i = nn >> 3;
    if (m < M_) {               // guard: m decode spans 2048 > M_
      float g  = (float)i - 128.0f;
      float kx = samples[2 * m + 0];
      float ky = samples[2 * m + 1];
      float sx, cx, sy, cy;
      sincospif(-2.0f * kx * g, &sx, &cx);
      sincospif(-2.0f * ky * g, &sy, &cy);
      int o = i * M_ + m;
      axtc_r[o] = (_Float16)cx; axtc_i[o] = (_Float16)(-sx);
      aytc_r[o] = (_Float16)cy; aytc_i[o] = (_Float16)(-sy);
    }
  } else {
    int nn = n - PH1_N - PH2_N;
    const int b  = nn >> 6;
    const int i0 = (nn & 7) * 32, j0 = ((nn >> 3) & 7) * 32;
    const int r = t >> 5, c = t & 31;
#pragma unroll
    for (int k = 0; k < 4; ++k) {
      int row = r + k * 8;
      tr[row][c] = xr[(size_t)b * IMG2 + (i0 + row) * IMG_ + j0 + c];
      ti[row][c] = xi[(size_t)b * IMG2 + (i0 + row) * IMG_ + j0 + c];
    }
    __syncthreads();
#pragma unroll
    for (int k = 0; k < 4; ++k) {
      int row = r + k * 8;
      xth_r[(size_t)b * IMG2 + (j0 + row) * IMG_ + i0 + c] = (_Float16)tr[c][row];
      xth_i[(size_t)b * IMG2 + (j0 + row) * IMG_ + i0 + c] = (_Float16)ti[c][row];
    }
  }
}

// ---------------------------------------------------------------------------
// LDS swizzle, per 32-half (64B) row of 4 16B chunks: physical chunk p of row
// r holds logical chunk p ^ ((r>>1)&3). Staging via global_load_lds writes
// lane-linear with pre-swizzled global source; ds_read_b128 frags read phys
// chunk q ^ ((lr>>1)&3). Zero bank conflicts (measured r1-r6).
// ---------------------------------------------------------------------------

// ---------------------------------------------------------------------------
// fwd_k: ROUND-3 VERSION VERBATIM (98 us measured — best anchor; the r5/r6
// variants regressed to 109/171 us).
//   kpart[jc][b][m] = sum_{j in jc half} Ay[m,j] * (sum_i Ax[m,i] * X_b[i,j])
// Grid 3840 1-D XCD-grouped; block 64m x 128j (one jc), 8 k-steps, (256,3),
// full unroll, epilogue once post-loop.
// ---------------------------------------------------------------------------
__global__ __launch_bounds__(256, 3) void fwd_k(
    const _Float16* __restrict__ axh_r, const _Float16* __restrict__ axh_i,
    const _Float16* __restrict__ ayh_r, const _Float16* __restrict__ ayh_i,
    const _Float16* __restrict__ xth_r, const _Float16* __restrict__ xth_i,
    float2* __restrict__ kpart) {
  __shared__ _Float16 lds[2][12288];   // 48 KB

  const int t  = threadIdx.x;
  const int w  = t >> 6;
  const int l  = t & 63;
  const int lr = l & 15;   // frag row within 16-tile; C col (j)
  const int q  = l >> 4;   // k-chunk; C row group (m)

  const int n     = blockIdx.x;        // 0..3839
  const int r     = n >> 3;            // 0..479
  const int b     = (n & 7) + 8 * (r / 60);
  const int inner = r % 60;
  const int m0    = (inner % 30) * 64;
  const int jc    = inner / 30;
  const int j0    = jc * 128;

  const int srow   = l >> 2;                      // staging row within 16
  const int schunk = (l & 3) ^ ((l >> 3) & 3);    // pre-swizzled global chunk
  const int gA     = srow * IMG_ + schunk * 8;    // halfs
  const int rc     = (q ^ ((lr >> 1) & 3)) << 3;  // frag-read swizzled chunk

  const floatx4 z4 = {0.f, 0.f, 0.f, 0.f};
  floatx4 accr[4][2], acci[4][2];
#pragma unroll
  for (int mt = 0; mt < 4; ++mt)
#pragma unroll
    for (int jt = 0; jt < 2; ++jt) { accr[mt][jt] = z4; acci[mt][jt] = z4; }

  auto stage = [&](int buf, int s) {
    const int col = s * 32;
    _Float16* L = lds[buf];
    const size_t offA = (size_t)(m0 + w * 16) * IMG_ + col + gA;
    gll16(axh_r + offA, L + 0    + w * 512);
    gll16(axh_i + offA, L + 2048 + w * 512);
    const size_t offB = (size_t)b * IMG2 + (size_t)(j0 + w * 32) * IMG_ + col + gA;
    gll16(xth_r + offB,             L + 4096 + w * 1024);
    gll16(xth_r + offB + 16 * IMG_, L + 4096 + w * 1024 + 512);
    gll16(xth_i + offB,             L + 8192 + w * 1024);
    gll16(xth_i + offB + 16 * IMG_, L + 8192 + w * 1024 + 512);
  };

  auto compute = [&](int buf) {
    const _Float16* L = lds[buf];
    half8 br[2], bi[2], nbi[2];
#pragma unroll
    for (int jt = 0; jt < 2; ++jt) {
      const int ro = (w * 32 + jt * 16 + lr) * 32 + rc;
      br[jt]  = *(const half8*)&L[4096 + ro];
      bi[jt]  = *(const half8*)&L[8192 + ro];
      nbi[jt] = -bi[jt];
    }
#pragma unroll
    for (int mt = 0; mt < 4; ++mt) {
      const int ro = (mt * 16 + lr) * 32 + rc;
      half8 ar = *(const half8*)&L[0 + ro];
      half8 ai = *(const half8*)&L[2048 + ro];
#pragma unroll
      for (int jt = 0; jt < 2; ++jt) {
        accr[mt][jt] = __builtin_amdgcn_mfma_f32_16x16x32_f16(ar, br[jt],  accr[mt][jt], 0, 0, 0);
        accr[mt][jt] = __builtin_amdgcn_mfma_f32_16x16x32_f16(ai, nbi[jt], accr[mt][jt], 0, 0, 0);
        acci[mt][jt] = __builtin_amdgcn_mfma_f32_16x16x32_f16(ar, bi[jt],  acci[mt][jt], 0, 0, 0);
        acci[mt][jt] = __builtin_amdgcn_mfma_f32_16x16x32_f16(ai, br[jt],  acci[mt][jt], 0, 0, 0);
      }
    }
  };

  stage(0, 0);
  __syncthreads();               // implicit vmcnt(0) drains global_load_lds
#pragma unroll
  for (int s = 0; s < 8; ++s) {
    const int buf = s & 1;
    if (s < 7) stage(buf ^ 1, s + 1);    // next-tile loads overlap MFMA
    compute(buf);
    __syncthreads();
  }

  // Epilogue (once, post-loop): kacc[m] += sum_j Ay[m,j]*T[m,j]
  float kr[4][4] = {}, ki[4][4] = {};
#pragma unroll
  for (int mt = 0; mt < 4; ++mt)
#pragma unroll
    for (int jt = 0; jt < 2; ++jt) {
      const int j = j0 + w * 32 + jt * 16 + lr;
#pragma unroll
      for (int reg = 0; reg < 4; ++reg) {
        const int m = m0 + mt * 16 + q * 4 + reg;
        const float yr = (float)ayh_r[m * IMG_ + j];
        const float yi = (float)ayh_i[m * IMG_ + j];
        const float tr = accr[mt][jt][reg], ti = acci[mt][jt][reg];
        kr[mt][reg] = fmaf(yr, tr, fmaf(-yi, ti, kr[mt][reg]));
        ki[mt][reg] = fmaf(yr, ti, fmaf(yi, tr, ki[mt][reg]));
      }
    }

#pragma unroll
  for (int mt = 0; mt < 4; ++mt)
#pragma unroll
    for (int reg = 0; reg < 4; ++reg)
#pragma unroll
      for (int off = 1; off < 16; off <<= 1) {
        kr[mt][reg] += __shfl_xor(kr[mt][reg], off);
        ki[mt][reg] += __shfl_xor(ki[mt][reg], off);
      }

  float2* scr = (float2*)&lds[0][0];
  if (lr == 0) {
#pragma unroll
    for (int mt = 0; mt < 4; ++mt)
#pragma unroll
      for (int reg = 0; reg < 4; ++reg)
        scr[w * 64 + mt * 16 + q * 4 + reg] = make_float2(kr[mt][reg], ki[mt][reg]);
  }
  __syncthreads();
  if (t < 64) {
    float sr = 0.f, si = 0.f;
#pragma unroll
    for (int ww = 0; ww < 4; ++ww) {
      const float2 p = scr[ww * 64 + t];
      sr += p.x; si += p.y;
    }
    kpart[((size_t)jc * B_ + b) * M_ + m0 + t] = make_float2(sr, si);
  }
}

// ---------------------------------------------------------------------------
// Combine jc partials, apply density, convert to f16 kw. (round-3 verbatim)
// ---------------------------------------------------------------------------
__global__ __launch_bounds__(256) void comb_k(
    const float2* __restrict__ kpart, const float* __restrict__ density,
    _Float16* __restrict__ kwh_r, _Float16* __restrict__ kwh_i) {
  const int idx = blockIdx.x * 256 + threadIdx.x;
  if (idx >= B_ * M_) return;
  const int m = idx % M_;
  const float2 p0 = kpart[idx];
  const float2 p1 = kpart[(size_t)B_ * M_ + idx];
  const float d = density[m];
  kwh_r[idx] = (_Float16)((p0.x + p1.x) * d);
  kwh_i[idx] = (_Float16)((p0.y + p1.y) * d);
}

// ---------------------------------------------------------------------------
// Adjoint NDFT via f16 MFMA — ROUND-7 REDESIGN: W in registers, not LDS.
//   out[b,i,j] = (1/IMG^2) sum_m conj(Ax)[m,i] * kw[b,m] * conj(Ay)[m,j]
// Theory: both GEMMs are LDS-read-bound (the 25-29% MfmaUtil ceiling matches
// 48KB-LDS-per-block-step arithmetic). Each wave now loads aytc/kw 16B-per-
// lane straight from global (L2-hot strips) and computes its own W-fragments
// in registers (2x redundant across the wi-pair; VALU pipe is idle anyway).
// LDS holds only the A double-buffer (16 KB); barrier protects only 2 gll16.
// Per step per wave: LDS 4 b128 (was 8), MFMA 16, acc only 32 VGPR.
// Block 64i x 64j, 4 waves (2wi x 2wj) of 32x32; K = 1920, 60 steps.
// Grid 1024 1-D XCD-grouped: xcd = n&7 owns combos {x, x+8} for all 64 b.
// ---------------------------------------------------------------------------
__global__ __launch_bounds__(256, 3) void adj_k(
    const _Float16* __restrict__ axtc_r, const _Float16* __restrict__ axtc_i,
    const _Float16* __restrict__ aytc_r, const _Float16* __restrict__ aytc_i,
    const _Float16* __restrict__ kwh_r, const _Float16* __restrict__ kwh_i,
    float* __restrict__ out) {
  __shared__ _Float16 lds[2][4096];    // 16 KB: {A_r, A_i} x dbuf

  const int t  = threadIdx.x;
  const int w  = t >> 6;
  const int l  = t & 63;
  const int lr = l & 15;
  const int q  = l >> 4;
  const int wi = w >> 1;               // 2 wave-rows (i)
  const int wj = w & 1;                // 2 wave-cols (j)

  const int n     = blockIdx.x;        // 0..1023
  const int xcd   = n & 7;
  const int r     = n >> 3;            // 0..127
  const int combo = xcd + 8 * (r >> 6);  // 0..15
  const int b     = r & 63;
  const int i0    = (combo >> 2) * 64;
  const int j0    = (combo & 3) * 64;

  const int srow   = l >> 2;
  const int schunk = (l & 3) ^ ((l >> 3) & 3);
  const int gA     = srow * M_ + schunk * 8;      // A row stride = 1920 halfs
  const int rc     = (q ^ ((lr >> 1) & 3)) << 3;

  // per-lane global row bases for the two j-fragment rows this lane owns
  const size_t yrow0 = (size_t)(j0 + wj * 32 + 0 * 16 + lr) * M_;
  const size_t yrow1 = (size_t)(j0 + wj * 32 + 1 * 16 + lr) * M_;
  const size_t cbase = (size_t)b * M_;

  const floatx4 z4 = {0.f, 0.f, 0.f, 0.f};
  floatx4 accr[2][2], acci[2][2];
#pragma unroll
  for (int mt = 0; mt < 2; ++mt)
#pragma unroll
    for (int jt = 0; jt < 2; ++jt) { accr[mt][jt] = z4; acci[mt][jt] = z4; }

  uint4 Yr[2], Yi[2], Cr, Ci;

  auto stageA = [&](int buf, int s) {
    const int mc = s * 32;
    _Float16* L = lds[buf];
    const size_t off = (size_t)(i0 + w * 16) * M_ + mc + gA;
    gll16(axtc_r + off, L + 0    + w * 512);
    gll16(axtc_i + off, L + 2048 + w * 512);
  };

  auto loadY = [&](int s) {   // 16B per lane, all straight from global/L2
    const int mc = s * 32 + q * 8;    // this lane's k-chunk
    Yr[0] = *(const uint4*)&aytc_r[yrow0 + mc];
    Yi[0] = *(const uint4*)&aytc_i[yrow0 + mc];
    Yr[1] = *(const uint4*)&aytc_r[yrow1 + mc];
    Yi[1] = *(const uint4*)&aytc_i[yrow1 + mc];
    Cr    = *(const uint4*)&kwh_r[cbase + mc];
    Ci    = *(const uint4*)&kwh_i[cbase + mc];
  };

  auto compute = [&](int buf) {
    // Build W = kw * conj(Ay) fragments in registers (packed f16 math)
    half8 br[2], bi2[2], nbi[2];
#pragma unroll
    for (int jt = 0; jt < 2; ++jt) {
      __half2 Wr[4], Wi4[4];
      const __half2* yr = (const __half2*)&Yr[jt];
      const __half2* yi = (const __half2*)&Yi[jt];
      const __half2* cr = (const __half2*)&Cr;
      const __half2* ci = (const __half2*)&Ci;
#pragma unroll
      for (int e = 0; e < 4; ++e) {
        Wr[e]  = __hsub2(__hmul2(cr[e], yr[e]), __hmul2(ci[e], yi[e]));
        Wi4[e] = __hfma2(cr[e], yi[e], __hmul2(ci[e], yr[e]));
      }
      br[jt]  = *(const half8*)&Wr[0];
      bi2[jt] = *(const half8*)&Wi4[0];
      nbi[jt] = -bi2[jt];
    }
    const _Float16* L = lds[buf];
#pragma unroll
    for (int mt = 0; mt < 2; ++mt) {
      const int ro = (wi * 32 + mt * 16 + lr) * 32 + rc;
      half8 ar = *(const half8*)&L[0 + ro];
      half8 ai = *(const half8*)&L[2048 + ro];
#pragma unroll
      for (int jt = 0; jt < 2; ++jt) {
        accr[mt][jt] = __builtin_amdgcn_mfma_f32_16x16x32_f16(ar, br[jt],  accr[mt][jt], 0, 0, 0);
        accr[mt][jt] = __builtin_amdgcn_mfma_f32_16x16x32_f16(ai, nbi[jt], accr[mt][jt], 0, 0, 0);
        acci[mt][jt] = __builtin_amdgcn_mfma_f32_16x16x32_f16(ar, bi2[jt], acci[mt][jt], 0, 0, 0);
        acci[mt][jt] = __builtin_amdgcn_mfma_f32_16x16x32_f16(ai, br[jt],  acci[mt][jt], 0, 0, 0);
      }
    }
  };

  loadY(0);
  stageA(0, 0);
  __syncthreads();
#pragma unroll 2
  for (int s = 0; s < 60; ++s) {
    const int buf = s & 1;
    if (s < 59) stageA(buf ^ 1, s + 1);
    compute(buf);                 // consumes Y regs into W, then MFMAs
    if (s < 59) loadY(s + 1);     // re-fill Y regs; overlaps barrier drain
    __syncthreads();
  }

  const float sc = 1.0f / (float)IMG2;
#pragma unroll
  for (int mt = 0; mt < 2; ++mt)
#pragma unroll
    for (int jt = 0; jt < 2; ++jt) {
      const int jg = j0 + wj * 32 + jt * 16 + lr;
#pragma unroll
      for (int reg = 0; reg < 4; ++reg) {
        const int ig = i0 + wi * 32 + mt * 16 + q * 4 + reg;
        float2 v = make_float2(accr[mt][jt][reg] * sc, acci[mt][jt][reg] * sc);
        *(float2*)&out[((size_t)(b * IMG_ + ig) * IMG_ + jg) * 2] = v;
      }
    }
}

// ---------------------------------------------------------------------------
// Launch: prep, fwd, comb, adj.
// ---------------------------------------------------------------------------
extern "C" void kernel_launch(void* const* d_in, const int* in_sizes, int n_in,
                              void* d_out, int out_size, void* d_ws, size_t ws_size,
                              hipStream_t stream) {
  (void)in_sizes; (void)n_in; (void)out_size; (void)ws_size;

  const float* xr      = (const float*)d_in[0];
  const float* xi      = (const float*)d_in[1];
  const float* samples = (const float*)d_in[2];
  const float* density = (const float*)d_in[3];
  float* out = (float*)d_out;

  // ws: 10 f16 arrays, 8.36 MB total
  _Float16* f = (_Float16*)d_ws;
  _Float16* axh_r  = f + 0 * MI_;
  _Float16* axh_i  = f + 1 * MI_;
  _Float16* ayh_r  = f + 2 * MI_;
  _Float16* ayh_i  = f + 3 * MI_;
  _Float16* axtc_r = f + 4 * MI_;
  _Float16* axtc_i = f + 5 * MI_;
  _Float16* aytc_r = f + 6 * MI_;
  _Float16* aytc_i = f + 7 * MI_;
  _Float16* kwh_r  = f + 8 * MI_;
  _Float16* kwh_i  = kwh_r + B_ * M_;

  // d_out parking: [0,16.7MB) X^T f16 (consumed by fwd_k);
  // [16.7,18.7MB) kpart f32 (consumed by comb_k); adj_k overwrites all after.
  _Float16* xth_r = (_Float16*)d_out;
  _Float16* xth_i = xth_r + (size_t)B_ * IMG2;
  float2*   kpart = (float2*)(xth_i + (size_t)B_ * IMG2);

  prep_k<<<PH1_N + PH2_N + XT_N, 256, 0, stream>>>(
      samples, xr, xi, axh_r, axh_i, ayh_r, ayh_i,
      axtc_r, axtc_i, aytc_r, aytc_i, xth_r, xth_i);
  fwd_k<<<3840, 256, 0, stream>>>(axh_r, axh_i, ayh_r, ayh_i,
                                  xth_r, xth_i, kpart);
  comb_k<<<(B_ * M_ + 255) / 256, 256, 0, stream>>>(kpart, density, kwh_r, kwh_i);
  adj_k<<<1024, 256, 0, stream>>>(axtc_r, axtc_i, aytc_r, aytc_i,
                                  kwh_r, kwh_i, out);
}

// Round 8
// 262.860 us; speedup vs baseline: 1.2664x; 1.2255x over previous
//
#include <hip/hip_runtime.h>
#include <hip/hip_bf16.h>
#include <hip/hip_fp16.h>

// Problem constants (match reference)
constexpr int IMG_ = 256;
constexpr int M_   = 1920;   // N_SHOTS * N_SAMPLES
constexpr int B_   = 64;
constexpr int MI_  = M_ * IMG_;          // 491520 elements per phase table
constexpr int IMG2 = IMG_ * IMG_;        // 65536

typedef _Float16 half8 __attribute__((ext_vector_type(8)));
typedef float    floatx4 __attribute__((ext_vector_type(4)));

// global -> LDS direct copy, 16B per lane; LDS dest is wave-uniform base + lane*16
__device__ __forceinline__ void gll16(const _Float16* g, _Float16* l) {
  __builtin_amdgcn_global_load_lds(
      (const __attribute__((address_space(1))) void*)g,
      (__attribute__((address_space(3))) void*)l, 16, 0, 0);
}

// ---------------------------------------------------------------------------
// prep_k: fused {phase1 | phase2 | x-transpose} by blockIdx range (r5-proven,
// with the PH2 m-guard). Saves 2 launches vs separate phase kernels.
// ---------------------------------------------------------------------------
constexpr int PH1_N = MI_ / 256;          // 1920
constexpr int PH2_N = 8 * IMG_;           // 2048
constexpr int XT_N  = 8 * 8 * B_;         // 4096

__global__ __launch_bounds__(256) void prep_k(
    const float* __restrict__ samples,
    const float* __restrict__ xr, const float* __restrict__ xi,
    _Float16* __restrict__ axh_r, _Float16* __restrict__ axh_i,
    _Float16* __restrict__ ayh_r, _Float16* __restrict__ ayh_i,
    _Float16* __restrict__ axtc_r, _Float16* __restrict__ axtc_i,
    _Float16* __restrict__ aytc_r, _Float16* __restrict__ aytc_i,
    _Float16* __restrict__ xth_r, _Float16* __restrict__ xth_i) {
  __shared__ float tr[32][33], ti[32][33];
  const int t = threadIdx.x;
  const int n = blockIdx.x;

  if (n < PH1_N) {
    int idx = n * 256 + t;
    int m = idx >> 8;
    int i = idx & 255;
    float g  = (float)i - 128.0f;
    float kx = samples[2 * m + 0];
    float ky = samples[2 * m + 1];
    float sx, cx, sy, cy;
    sincospif(-2.0f * kx * g, &sx, &cx);
    sincospif(-2.0f * ky * g, &sy, &cy);
    axh_r[idx] = (_Float16)cx; axh_i[idx] = (_Float16)sx;
    ayh_r[idx] = (_Float16)cy; ayh_i[idx] = (_Float16)sy;
  } else if (n < PH1_N + PH2_N) {
    int nn = n - PH1_N;
    int m = (nn & 7) * 256 + t;
    int i = nn >> 3;
    if (m < M_) {               // guard: m decode spans 2048 > M_
      float g  = (float)i - 128.0f;
      float kx = samples[2 * m + 0];
      float ky = samples[2 * m + 1];
      float sx, cx, sy, cy;
      sincospif(-2.0f * kx * g, &sx, &cx);
      sincospif(-2.0f * ky * g, &sy, &cy);
      int o = i * M_ + m;
      axtc_r[o] = (_Float16)cx; axtc_i[o] = (_Float16)(-sx);
      aytc_r[o] = (_Float16)cy; aytc_i[o] = (_Float16)(-sy);
    }
  } else {
    int nn = n - PH1_N - PH2_N;
    const int b  = nn >> 6;
    const int i0 = (nn & 7) * 32, j0 = ((nn >> 3) & 7) * 32;
    const int r = t >> 5, c = t & 31;
#pragma unroll
    for (int k = 0; k < 4; ++k) {
      int row = r + k * 8;
      tr[row][c] = xr[(size_t)b * IMG2 + (i0 + row) * IMG_ + j0 + c];
      ti[row][c] = xi[(size_t)b * IMG2 + (i0 + row) * IMG_ + j0 + c];
    }
    __syncthreads();
#pragma unroll
    for (int k = 0; k < 4; ++k) {
      int row = r + k * 8;
      xth_r[(size_t)b * IMG2 + (j0 + row) * IMG_ + i0 + c] = (_Float16)tr[c][row];
      xth_i[(size_t)b * IMG2 + (j0 + row) * IMG_ + i0 + c] = (_Float16)ti[c][row];
    }
  }
}

// ---------------------------------------------------------------------------
// LDS swizzle (both GEMMs), per 32-half (64B) row of 4 16B chunks: physical
// chunk p of row r holds logical chunk p ^ ((r>>1)&3). Staging via
// global_load_lds writes lane-linear with pre-swizzled global source;
// ds_read_b128 frags read phys chunk q ^ ((lr>>1)&3). Zero bank conflicts
// (measured r1-r7).
// ---------------------------------------------------------------------------

// ---------------------------------------------------------------------------
// fwd_k: ROUND-3 VERSION VERBATIM — 98.5 us measured, best fwd across 7
// rounds. (256,3) + full unroll; the ~48 MB scratch WRITE is a known benign
// spill: the no-spill variant (r6: uncapped VGPR 148, unroll 2) ran 171 us
// because occupancy collapsed. Do not "fix" the spill.
//   kpart[jc][b][m] = sum_{j in jc half} Ay[m,j] * (sum_i Ax[m,i] * X_b[i,j])
// Grid 3840 1-D XCD-grouped; block 64m x 128j (one jc), 8 k-steps.
// ---------------------------------------------------------------------------
__global__ __launch_bounds__(256, 3) void fwd_k(
    const _Float16* __restrict__ axh_r, const _Float16* __restrict__ axh_i,
    const _Float16* __restrict__ ayh_r, const _Float16* __restrict__ ayh_i,
    const _Float16* __restrict__ xth_r, const _Float16* __restrict__ xth_i,
    float2* __restrict__ kpart) {
  __shared__ _Float16 lds[2][12288];   // 48 KB

  const int t  = threadIdx.x;
  const int w  = t >> 6;
  const int l  = t & 63;
  const int lr = l & 15;   // frag row within 16-tile; C col (j)
  const int q  = l >> 4;   // k-chunk; C row group (m)

  const int n     = blockIdx.x;        // 0..3839
  const int r     = n >> 3;            // 0..479
  const int b     = (n & 7) + 8 * (r / 60);
  const int inner = r % 60;
  const int m0    = (inner % 30) * 64;
  const int jc    = inner / 30;
  const int j0    = jc * 128;

  const int srow   = l >> 2;                      // staging row within 16
  const int schunk = (l & 3) ^ ((l >> 3) & 3);    // pre-swizzled global chunk
  const int gA     = srow * IMG_ + schunk * 8;    // halfs
  const int rc     = (q ^ ((lr >> 1) & 3)) << 3;  // frag-read swizzled chunk

  const floatx4 z4 = {0.f, 0.f, 0.f, 0.f};
  floatx4 accr[4][2], acci[4][2];
#pragma unroll
  for (int mt = 0; mt < 4; ++mt)
#pragma unroll
    for (int jt = 0; jt < 2; ++jt) { accr[mt][jt] = z4; acci[mt][jt] = z4; }

  auto stage = [&](int buf, int s) {
    const int col = s * 32;
    _Float16* L = lds[buf];
    const size_t offA = (size_t)(m0 + w * 16) * IMG_ + col + gA;
    gll16(axh_r + offA, L + 0    + w * 512);
    gll16(axh_i + offA, L + 2048 + w * 512);
    const size_t offB = (size_t)b * IMG2 + (size_t)(j0 + w * 32) * IMG_ + col + gA;
    gll16(xth_r + offB,             L + 4096 + w * 1024);
    gll16(xth_r + offB + 16 * IMG_, L + 4096 + w * 1024 + 512);
    gll16(xth_i + offB,             L + 8192 + w * 1024);
    gll16(xth_i + offB + 16 * IMG_, L + 8192 + w * 1024 + 512);
  };

  auto compute = [&](int buf) {
    const _Float16* L = lds[buf];
    half8 br[2], bi[2], nbi[2];
#pragma unroll
    for (int jt = 0; jt < 2; ++jt) {
      const int ro = (w * 32 + jt * 16 + lr) * 32 + rc;
      br[jt]  = *(const half8*)&L[4096 + ro];
      bi[jt]  = *(const half8*)&L[8192 + ro];
      nbi[jt] = -bi[jt];
    }
#pragma unroll
    for (int mt = 0; mt < 4; ++mt) {
      const int ro = (mt * 16 + lr) * 32 + rc;
      half8 ar = *(const half8*)&L[0 + ro];
      half8 ai = *(const half8*)&L[2048 + ro];
#pragma unroll
      for (int jt = 0; jt < 2; ++jt) {
        accr[mt][jt] = __builtin_amdgcn_mfma_f32_16x16x32_f16(ar, br[jt],  accr[mt][jt], 0, 0, 0);
        accr[mt][jt] = __builtin_amdgcn_mfma_f32_16x16x32_f16(ai, nbi[jt], accr[mt][jt], 0, 0, 0);
        acci[mt][jt] = __builtin_amdgcn_mfma_f32_16x16x32_f16(ar, bi[jt],  acci[mt][jt], 0, 0, 0);
        acci[mt][jt] = __builtin_amdgcn_mfma_f32_16x16x32_f16(ai, br[jt],  acci[mt][jt], 0, 0, 0);
      }
    }
  };

  stage(0, 0);
  __syncthreads();               // implicit vmcnt(0) drains global_load_lds
#pragma unroll
  for (int s = 0; s < 8; ++s) {
    const int buf = s & 1;
    if (s < 7) stage(buf ^ 1, s + 1);    // next-tile loads overlap MFMA
    compute(buf);
    __syncthreads();
  }

  // Epilogue (once, post-loop): kacc[m] += sum_j Ay[m,j]*T[m,j]
  float kr[4][4] = {}, ki[4][4] = {};
#pragma unroll
  for (int mt = 0; mt < 4; ++mt)
#pragma unroll
    for (int jt = 0; jt < 2; ++jt) {
      const int j = j0 + w * 32 + jt * 16 + lr;
#pragma unroll
      for (int reg = 0; reg < 4; ++reg) {
        const int m = m0 + mt * 16 + q * 4 + reg;
        const float yr = (float)ayh_r[m * IMG_ + j];
        const float yi = (float)ayh_i[m * IMG_ + j];
        const float tr = accr[mt][jt][reg], ti = acci[mt][jt][reg];
        kr[mt][reg] = fmaf(yr, tr, fmaf(-yi, ti, kr[mt][reg]));
        ki[mt][reg] = fmaf(yr, ti, fmaf(yi, tr, ki[mt][reg]));
      }
    }

#pragma unroll
  for (int mt = 0; mt < 4; ++mt)
#pragma unroll
    for (int reg = 0; reg < 4; ++reg)
#pragma unroll
      for (int off = 1; off < 16; off <<= 1) {
        kr[mt][reg] += __shfl_xor(kr[mt][reg], off);
        ki[mt][reg] += __shfl_xor(ki[mt][reg], off);
      }

  float2* scr = (float2*)&lds[0][0];
  if (lr == 0) {
#pragma unroll
    for (int mt = 0; mt < 4; ++mt)
#pragma unroll
      for (int reg = 0; reg < 4; ++reg)
        scr[w * 64 + mt * 16 + q * 4 + reg] = make_float2(kr[mt][reg], ki[mt][reg]);
  }
  __syncthreads();
  if (t < 64) {
    float sr = 0.f, si = 0.f;
#pragma unroll
    for (int ww = 0; ww < 4; ++ww) {
      const float2 p = scr[ww * 64 + t];
      sr += p.x; si += p.y;
    }
    kpart[((size_t)jc * B_ + b) * M_ + m0 + t] = make_float2(sr, si);
  }
}

// ---------------------------------------------------------------------------
// Combine jc partials, apply density, convert to f16 kw. (round-3 verbatim)
// ---------------------------------------------------------------------------
__global__ __launch_bounds__(256) void comb_k(
    const float2* __restrict__ kpart, const float* __restrict__ density,
    _Float16* __restrict__ kwh_r, _Float16* __restrict__ kwh_i) {
  const int idx = blockIdx.x * 256 + threadIdx.x;
  if (idx >= B_ * M_) return;
  const int m = idx % M_;
  const float2 p0 = kpart[idx];
  const float2 p1 = kpart[(size_t)B_ * M_ + idx];
  const float d = density[m];
  kwh_r[idx] = (_Float16)((p0.x + p1.x) * d);
  kwh_i[idx] = (_Float16)((p0.y + p1.y) * d);
}

// ---------------------------------------------------------------------------
// adj_k: ROUND-3 VERSION VERBATIM (the best total, 264 us, used this one;
// the r4-r6 64x64 retile measured ~115 us and the r7 W-in-regs redesign 166
// us — both worse than this r3 structure's inferred ~90-100 us).
//   out[b,i,j] = (1/IMG^2) sum_m conj(Ax)[m,i] * kw[b,m] * conj(Ay)[m,j]
// Block 256 thr = 4 waves; block tile 64i x 128j (wave w owns j-slice w*32);
// wave tile 64i x 32j -> acc 64 VGPR. K = 1920 m, 60 double-buffered steps.
// W = kw*conj(Ay) computed in regs (loads issued before compute, swizzled
// ds_write after). Grid (4, 2, 64) = 512 blocks.
// ---------------------------------------------------------------------------
__global__ __launch_bounds__(256, 3) void adj_k(
    const _Float16* __restrict__ axtc_r, const _Float16* __restrict__ axtc_i,
    const _Float16* __restrict__ aytc_r, const _Float16* __restrict__ aytc_i,
    const _Float16* __restrict__ kwh_r, const _Float16* __restrict__ kwh_i,
    float* __restrict__ out) {
  __shared__ _Float16 lds[2][12288];   // 48 KB

  const int t  = threadIdx.x;
  const int w  = t >> 6;
  const int l  = t & 63;
  const int lr = l & 15;
  const int q  = l >> 4;
  const int b  = blockIdx.z;
  const int i0 = blockIdx.x * 64;
  const int j0 = blockIdx.y * 128;

  const int srow   = l >> 2;
  const int schunk = (l & 3) ^ ((l >> 3) & 3);
  const int gA     = srow * M_ + schunk * 8;      // A row stride = 1920 halfs
  const int rc     = (q ^ ((lr >> 1) & 3)) << 3;

  // W staging: thread -> (j-row = t>>1, m-half = t&1); swizzled b128 writes
  const int wrow = t >> 1;
  const int wh   = t & 1;
  const int wp   = (wrow >> 1) & 3;
  const int wc0  = ((2 * wh + 0) ^ wp) << 3;
  const int wc1  = ((2 * wh + 1) ^ wp) << 3;

  const floatx4 z4 = {0.f, 0.f, 0.f, 0.f};
  floatx4 accr[4][2], acci[4][2];
#pragma unroll
  for (int mt = 0; mt < 4; ++mt)
#pragma unroll
    for (int jt = 0; jt < 2; ++jt) { accr[mt][jt] = z4; acci[mt][jt] = z4; }

  uint4 Yr0, Yr1, Yi0, Yi1, Cr0, Cr1, Ci0, Ci1;

  auto stageA = [&](int buf, int s) {
    const int mc = s * 32;
    _Float16* L = lds[buf];
    const size_t off = (size_t)(i0 + w * 16) * M_ + mc + gA;
    gll16(axtc_r + off, L + 0    + w * 512);
    gll16(axtc_i + off, L + 2048 + w * 512);
  };

  auto loadW = [&](int s) {   // issue early; consumed by writeW after compute
    const int mc = s * 32 + wh * 16;
    const size_t oy = (size_t)(j0 + wrow) * M_ + mc;
    const size_t oc = (size_t)b * M_ + mc;
    Yr0 = *(const uint4*)&aytc_r[oy];  Yr1 = *(const uint4*)&aytc_r[oy + 8];
    Yi0 = *(const uint4*)&aytc_i[oy];  Yi1 = *(const uint4*)&aytc_i[oy + 8];
    Cr0 = *(const uint4*)&kwh_r[oc];   Cr1 = *(const uint4*)&kwh_r[oc + 8];
    Ci0 = *(const uint4*)&kwh_i[oc];   Ci1 = *(const uint4*)&kwh_i[oc + 8];
  };

  auto writeW = [&](int buf) {
    __half2 Wr0[4], Wi0[4], Wr1[4], Wi1[4];
    {
      const __half2* yr = (const __half2*)&Yr0; const __half2* yi = (const __half2*)&Yi0;
      const __half2* cr = (const __half2*)&Cr0; const __half2* ci = (const __half2*)&Ci0;
#pragma unroll
      for (int e = 0; e < 4; ++e) {
        Wr0[e] = __hsub2(__hmul2(cr[e], yr[e]), __hmul2(ci[e], yi[e]));
        Wi0[e] = __hfma2(cr[e], yi[e], __hmul2(ci[e], yr[e]));
      }
    }
    {
      const __half2* yr = (const __half2*)&Yr1; const __half2* yi = (const __half2*)&Yi1;
      const __half2* cr = (const __half2*)&Cr1; const __half2* ci = (const __half2*)&Ci1;
#pragma unroll
      for (int e = 0; e < 4; ++e) {
        Wr1[e] = __hsub2(__hmul2(cr[e], yr[e]), __hmul2(ci[e], yi[e]));
        Wi1[e] = __hfma2(cr[e], yi[e], __hmul2(ci[e], yr[e]));
      }
    }
    _Float16* Lr = lds[buf] + 4096;
    _Float16* Li = lds[buf] + 8192;
    const int rb = wrow * 32;
    *(uint4*)&Lr[rb + wc0] = *(const uint4*)&Wr0[0];
    *(uint4*)&Lr[rb + wc1] = *(const uint4*)&Wr1[0];
    *(uint4*)&Li[rb + wc0] = *(const uint4*)&Wi0[0];
    *(uint4*)&Li[rb + wc1] = *(const uint4*)&Wi1[0];
  };

  auto compute = [&](int buf) {
    const _Float16* L = lds[buf];
    half8 br[2], bi[2], nbi[2];
#pragma unroll
    for (int jt = 0; jt < 2; ++jt) {
      const int ro = (w * 32 + jt * 16 + lr) * 32 + rc;
      br[jt]  = *(const half8*)&L[4096 + ro];
      bi[jt]  = *(const half8*)&L[8192 + ro];
      nbi[jt] = -bi[jt];
    }
#pragma unroll
    for (int mt = 0; mt < 4; ++mt) {
      const int ro = (mt * 16 + lr) * 32 + rc;
      half8 ar = *(const half8*)&L[0 + ro];
      half8 ai = *(const half8*)&L[2048 + ro];
#pragma unroll
      for (int jt = 0; jt < 2; ++jt) {
        accr[mt][jt] = __builtin_amdgcn_mfma_f32_16x16x32_f16(ar, br[jt],  accr[mt][jt], 0, 0, 0);
        accr[mt][jt] = __builtin_amdgcn_mfma_f32_16x16x32_f16(ai, nbi[jt], accr[mt][jt], 0, 0, 0);
        acci[mt][jt] = __builtin_amdgcn_mfma_f32_16x16x32_f16(ar, bi[jt],  acci[mt][jt], 0, 0, 0);
        acci[mt][jt] = __builtin_amdgcn_mfma_f32_16x16x32_f16(ai, br[jt],  acci[mt][jt], 0, 0, 0);
      }
    }
  };

  loadW(0);
  stageA(0, 0);
  writeW(0);
  __syncthreads();
#pragma unroll 2
  for (int s = 0; s < 60; ++s) {
    const int buf = s & 1;
    if (s < 59) { stageA(buf ^ 1, s + 1); loadW(s + 1); }
    compute(buf);
    if (s < 59) writeW(buf ^ 1);
    __syncthreads();
  }

  const float sc = 1.0f / (float)IMG2;
#pragma unroll
  for (int mt = 0; mt < 4; ++mt)
#pragma unroll
    for (int jt = 0; jt < 2; ++jt) {
      const int jg = j0 + w * 32 + jt * 16 + lr;
#pragma unroll
      for (int reg = 0; reg < 4; ++reg) {
        const int ig = i0 + mt * 16 + q * 4 + reg;
        float2 v = make_float2(accr[mt][jt][reg] * sc, acci[mt][jt][reg] * sc);
        *(float2*)&out[((size_t)(b * IMG_ + ig) * IMG_ + jg) * 2] = v;
      }
    }
}

// ---------------------------------------------------------------------------
// Launch: prep, fwd, comb, adj (4 kernels).
// ---------------------------------------------------------------------------
extern "C" void kernel_launch(void* const* d_in, const int* in_sizes, int n_in,
                              void* d_out, int out_size, void* d_ws, size_t ws_size,
                              hipStream_t stream) {
  (void)in_sizes; (void)n_in; (void)out_size; (void)ws_size;

  const float* xr      = (const float*)d_in[0];
  const float* xi      = (const float*)d_in[1];
  const float* samples = (const float*)d_in[2];
  const float* density = (const float*)d_in[3];
  float* out = (float*)d_out;

  // ws: 10 f16 arrays, 8.36 MB total
  _Float16* f = (_Float16*)d_ws;
  _Float16* axh_r  = f + 0 * MI_;
  _Float16* axh_i  = f + 1 * MI_;
  _Float16* ayh_r  = f + 2 * MI_;
  _Float16* ayh_i  = f + 3 * MI_;
  _Float16* axtc_r = f + 4 * MI_;
  _Float16* axtc_i = f + 5 * MI_;
  _Float16* aytc_r = f + 6 * MI_;
  _Float16* aytc_i = f + 7 * MI_;
  _Float16* kwh_r  = f + 8 * MI_;
  _Float16* kwh_i  = kwh_r + B_ * M_;

  // d_out parking: [0,16.7MB) X^T f16 (consumed by fwd_k);
  // [16.7,18.7MB) kpart f32 (consumed by comb_k); adj_k overwrites all after.
  _Float16* xth_r = (_Float16*)d_out;
  _Float16* xth_i = xth_r + (size_t)B_ * IMG2;
  float2*   kpart = (float2*)(xth_i + (size_t)B_ * IMG2);

  prep_k<<<PH1_N + PH2_N + XT_N, 256, 0, stream>>>(
      samples, xr, xi, axh_r, axh_i, ayh_r, ayh_i,
      axtc_r, axtc_i, aytc_r, aytc_i, xth_r, xth_i);
  fwd_k<<<3840, 256, 0, stream>>>(axh_r, axh_i, ayh_r, ayh_i,
                                  xth_r, xth_i, kpart);
  comb_k<<<(B_ * M_ + 255) / 256, 256, 0, stream>>>(kpart, density, kwh_r, kwh_i);
  adj_k<<<dim3(4, 2, B_), 256, 0, stream>>>(axtc_r, axtc_i, aytc_r, aytc_i,
                                            kwh_r, kwh_i, out);
}